// Round 7
// baseline (124.752 us; speedup 1.0000x reference)
//
#include <hip/hip_runtime.h>
#include <hip/hip_bf16.h>

#define EPSF 1e-8f

typedef short bf16x8 __attribute__((ext_vector_type(8)));
typedef float f32x4 __attribute__((ext_vector_type(4)));

// Workspace:
//   xu   [loc][cp=0..63][ci=0..31]  u32 = (bf16 c=2cp | bf16 c=2cp+1 <<16)   64 MiB
//   Bpk  [loc][cj=0..31][cip=0..15] u32 = (bf16 B[ci=2cip] | B[2cip+1]<<16)  16 MiB
//   shat [loc][c] f32 (4 MiB)
//   pm0/ps0 [1024][32] ; pm1/ps1/pt1 [8192][32] ; sm*/siz*/entp [256]

__device__ __forceinline__ float bflo(unsigned u) { return __uint_as_float(u << 16); }
__device__ __forceinline__ float bfhi(unsigned u) { return __uint_as_float(u & 0xffff0000u); }
__device__ __forceinline__ float bf16f(unsigned short u) { return __uint_as_float((unsigned)u << 16); }
__device__ __forceinline__ unsigned bfpack2(float a, float b) {
    return (__float_as_uint(a) >> 16) | (__float_as_uint(b) & 0xffff0000u);
}
__device__ __forceinline__ float fastrcp(float x) { return __builtin_amdgcn_rcpf(x); }

// ---------------------------------------------------------------------------
// K1: MFMA conv + iter0 + B1.  The conv is a 27x128 matmul applied to every
// (loc,ci) tap-vector: n=(w,ci), K=27 pad 32, M(c)=128.  Block = (b,h,4 w's),
// grid 2048, 256 threads (4 waves).  Weights live in 32 VGPRs/lane (8 B-frags).
// Per wave-round: 1 ds_read_b128 A-frag + 8 MFMA -> 16n x 128c.
__global__ __launch_bounds__(256, 4) void k_conv_mfma(const float* __restrict__ in,
                                                      const float* __restrict__ cw,
                                                      const float* __restrict__ cb,
                                                      unsigned* __restrict__ xu,
                                                      unsigned* __restrict__ Bpk) {
    __shared__ __align__(16) unsigned char smem[40960];
    unsigned short* T  = (unsigned short*)smem;            // [128 n][40 k] bf16
    unsigned short* WF = (unsigned short*)(smem + 10240);  // [128 c][40 k] bf16
    float*    slab = (float*)(smem + 20480);               // [288][12] f32 (prologue)
    unsigned* pack = (unsigned*)(smem + 20480);            // [2][64][36] u32 (rounds)
    float*    shl  = (float*)(smem + 38912);               // [4][128] squash table

    const int t = threadIdx.x;
    const int bid = blockIdx.x;                  // (b,h,wq): wq = 0..7
    const int bh = bid >> 3, b = bh >> 5, h = bh & 31;
    const int w0 = (bid & 7) << 2;

    // ---- stage input slab (coalesced float4, zero-padded OOB) -------------
    for (int j = t; j < 864; j += 256) {
        const int r = j / 3, q = j - r * 3;
        const int ci2 = r / 9, rem = r - ci2 * 9, kd = rem / 3, dy = rem - kd * 3;
        const int y = h + dy - 1;
        const int x0 = w0 - 4 + q * 4;
        float4 f = {0.f, 0.f, 0.f, 0.f};
        if ((unsigned)y < 32u && (unsigned)x0 < 32u)
            f = *reinterpret_cast<const float4*>(
                in + (((size_t)(b * 32 + ci2) * 8 + kd) * 32 + y) * 32 + x0);
        *reinterpret_cast<float4*>(slab + r * 12 + q * 4) = f;
    }
    __syncthreads();

    // ---- build T (lower 128 threads) and WF (upper 128) in parallel -------
    float vsum[27];
    if (t < 128) {
        const int ci = t & 31, lw = t >> 5;      // n = lw*32+ci = t
        float v[27];
#pragma unroll
        for (int kd = 0; kd < 3; ++kd)
#pragma unroll
            for (int dy = 0; dy < 3; ++dy)
#pragma unroll
                for (int dx = 0; dx < 3; ++dx)
                    v[kd * 9 + dy * 3 + dx] = slab[(ci * 9 + kd * 3 + dy) * 12 + lw + 3 + dx];
#pragma unroll
        for (int k = 0; k < 27; ++k) {           // tap sum over 32 ci lanes
            float r = v[k];
            r += __shfl_xor(r, 1); r += __shfl_xor(r, 2); r += __shfl_xor(r, 4);
            r += __shfl_xor(r, 8); r += __shfl_xor(r, 16);
            vsum[k] = r;
        }
        unsigned rowu[20];
#pragma unroll
        for (int j = 0; j < 13; ++j) rowu[j] = bfpack2(v[2 * j], v[2 * j + 1]);
        rowu[13] = bfpack2(v[26], 0.0f);
#pragma unroll
        for (int j = 14; j < 20; ++j) rowu[j] = 0u;
        uint4* dst = reinterpret_cast<uint4*>(T + t * 40);
#pragma unroll
        for (int j = 0; j < 5; ++j)
            dst[j] = make_uint4(rowu[4 * j], rowu[4 * j + 1], rowu[4 * j + 2], rowu[4 * j + 3]);
    } else {
        const int c = t - 128;
        float wv[27];
#pragma unroll
        for (int k = 0; k < 27; ++k) wv[k] = cw[c * 27 + k];
        unsigned rowu[20];
#pragma unroll
        for (int j = 0; j < 13; ++j) rowu[j] = bfpack2(wv[2 * j], wv[2 * j + 1]);
        rowu[13] = bfpack2(wv[26], 0.0f);
#pragma unroll
        for (int j = 14; j < 20; ++j) rowu[j] = 0u;
        uint4* dst = reinterpret_cast<uint4*>(WF + c * 40);
#pragma unroll
        for (int j = 0; j < 5; ++j)
            dst[j] = make_uint4(rowu[4 * j], rowu[4 * j + 1], rowu[4 * j + 2], rowu[4 * j + 3]);
    }
    __syncthreads();

    // ---- squash table (iter0 uniform-k identity) + weight fragments -------
    if (t < 128) {
        const int ci = t & 31, lw = t >> 5;
#pragma unroll
        for (int qc = 0; qc < 4; ++qc) {
            const int c = ci * 4 + qc;
            float acc = 32.0f * cb[c];
#pragma unroll
            for (int k = 0; k < 27; ++k) acc = fmaf(bf16f(WF[c * 40 + k]), vsum[k], acc);
            const float S = acc * (1.0f / 32768.0f);
            shl[lw * 128 + c] = fabsf(S) * S * fastrcp(1.0f + S * S + EPSF);
        }
    }
    const int lane = t & 63, wv4 = t >> 6;
    bf16x8 wfr[8];
#pragma unroll
    for (int q = 0; q < 8; ++q) {
        const int c = q * 16 + (lane & 15);
        wfr[q] = *reinterpret_cast<const bf16x8*>(WF + c * 40 + (lane >> 4) * 8);
    }
    __syncthreads();

    // ---- 2 rounds x (4 waves x 16n x 128c) ---------------------------------
    for (int r = 0; r < 2; ++r) {
        const int slot = wv4 >> 1;
        const int ci0w = (wv4 & 1) * 16;
        const int nbase = (2 * r + slot) * 32 + ci0w;
        const bf16x8 af = *reinterpret_cast<const bf16x8*>(
            T + (nbase + (lane & 15)) * 40 + (lane >> 4) * 8);
        f32x4 acc[8];
#pragma unroll
        for (int q = 0; q < 8; ++q) acc[q] = (f32x4){0.f, 0.f, 0.f, 0.f};
#pragma unroll
        for (int q = 0; q < 8; ++q)
            acc[q] = __builtin_amdgcn_mfma_f32_16x16x32_bf16(af, wfr[q], acc[q], 0, 0, 0);

        // pack D -> LDS: pair channel columns via shfl_xor(1); lane-parity split
#pragma unroll
        for (int q = 0; q < 8; ++q) {
            const int cp = q * 8 + ((lane & 15) >> 1);
#pragma unroll
            for (int e = 0; e < 4; ++e) {
                const float val = acc[q][e];
                const float pv = __shfl_xor(val, 1);
                const unsigned pk = (lane & 1) ? bfpack2(pv, val) : bfpack2(val, pv);
                if ((e & 1) == (lane & 1)) {
                    const int ci = ci0w + (lane >> 4) * 4 + e;
                    pack[slot * 2304 + cp * 36 + ci] = pk;
                }
            }
        }
        __syncthreads();

        // cooperative readout: coalesced xu write + B1 (+bf16 pack) ----------
        {
            const int slot2 = t >> 7, cp2 = (t & 127) >> 1, ci0 = (t & 1) * 16;
            const size_t locg = (size_t)bh * 32 + w0 + 2 * r + slot2;
            uint4 pk4[4];
#pragma unroll
            for (int k = 0; k < 4; ++k)
                pk4[k] = *reinterpret_cast<const uint4*>(pack + slot2 * 2304 + cp2 * 36 + ci0 + 4 * k);
            uint4* gx = reinterpret_cast<uint4*>(xu + locg * 2048 + cp2 * 32 + ci0);
#pragma unroll
            for (int k = 0; k < 4; ++k) gx[k] = pk4[k];

            const float sa = shl[(2 * r + slot2) * 128 + 2 * cp2];
            const float sb = shl[(2 * r + slot2) * 128 + 2 * cp2 + 1];
            float d[16];
#pragma unroll
            for (int k = 0; k < 4; ++k) {
                const unsigned uu[4] = {pk4[k].x, pk4[k].y, pk4[k].z, pk4[k].w};
#pragma unroll
                for (int e = 0; e < 4; ++e)
                    d[4 * k + e] = fmaf(sa, bflo(uu[e]), sb * bfhi(uu[e]));
            }
#pragma unroll
            for (int j = 0; j < 16; ++j) d[j] += __shfl_xor(d[j], 2);   // cp-pair -> cj
            if ((t & 2) == 0) {
                unsigned opk[8];
#pragma unroll
                for (int e = 0; e < 8; ++e) opk[e] = bfpack2(d[2 * e], d[2 * e + 1]);
                uint4* gB = reinterpret_cast<uint4*>(Bpk + locg * 512 + (cp2 >> 1) * 16 + (t & 1) * 8);
                gB[0] = make_uint4(opk[0], opk[1], opk[2], opk[3]);
                gB[1] = make_uint4(opk[4], opk[5], opk[6], opk[7]);
            }
        }
        __syncthreads();
    }
}

// ---------------------------------------------------------------------------
// K1b: stats0 partials from Bpk. grid 1024 (8 locs each), per-ci max/sumexp.
__global__ __launch_bounds__(256) void k_bstats(const unsigned* __restrict__ Bpk,
                                                float* __restrict__ pm0,
                                                float* __restrict__ ps0) {
    const int t = threadIdx.x;
    const uint4* Bp4 = reinterpret_cast<const uint4*>(Bpk) + (size_t)blockIdx.x * 1024;
    uint4 vq[4];
#pragma unroll
    for (int j = 0; j < 4; ++j) vq[j] = Bp4[t + 256 * j];
    float m8[8], s8[8];
#pragma unroll
    for (int i = 0; i < 8; ++i) { m8[i] = -1e30f; s8[i] = 0.0f; }
#pragma unroll
    for (int j = 0; j < 4; ++j) {
        const unsigned uu[4] = {vq[j].x, vq[j].y, vq[j].z, vq[j].w};
#pragma unroll
        for (int e = 0; e < 4; ++e) {
            m8[2 * e]     = fmaxf(m8[2 * e],     bflo(uu[e]));
            m8[2 * e + 1] = fmaxf(m8[2 * e + 1], bfhi(uu[e]));
        }
    }
#pragma unroll
    for (int j = 0; j < 4; ++j) {
        const unsigned uu[4] = {vq[j].x, vq[j].y, vq[j].z, vq[j].w};
#pragma unroll
        for (int e = 0; e < 4; ++e) {
            s8[2 * e]     += __expf(bflo(uu[e]) - m8[2 * e]);
            s8[2 * e + 1] += __expf(bfhi(uu[e]) - m8[2 * e + 1]);
        }
    }
    __shared__ float redm[256][9], reds[256][9];
#pragma unroll
    for (int i = 0; i < 8; ++i) { redm[t][i] = m8[i]; reds[t][i] = s8[i]; }
    __syncthreads();
    for (int off = 128; off >= 4; off >>= 1) {
        if (t < off) {
#pragma unroll
            for (int i = 0; i < 8; ++i) {
                const float ma = redm[t][i], mb = redm[t + off][i];
                const float nm = fmaxf(ma, mb);
                reds[t][i] = reds[t][i] * __expf(ma - nm) + reds[t + off][i] * __expf(mb - nm);
                redm[t][i] = nm;
            }
        }
        __syncthreads();
    }
    if (t < 4) {
#pragma unroll
        for (int i = 0; i < 8; ++i) {
            pm0[blockIdx.x * 32 + t * 8 + i] = redm[t][i];
            ps0[blockIdx.x * 32 + t * 8 + i] = reds[t][i];
        }
    }
}

// ---------------------------------------------------------------------------
// Combine NPART partials per (b,ci) -> sm, siz (+ entropy partial if ENT).
template <int NPART, bool ENT>
__global__ __launch_bounds__(256) void k_comb(const float* __restrict__ pm,
                                              const float* __restrict__ ps,
                                              const float* __restrict__ pt,
                                              float* __restrict__ sm,
                                              float* __restrict__ siz,
                                              float* __restrict__ entp) {
    const int b = blockIdx.x, t = threadIdx.x;
    const int ci = t & 31, seg = t >> 5;
    constexpr int PER = NPART / 8;
    __shared__ float red[3][8][33];

    float M = -1e30f;
    for (int k = 0; k < PER; ++k)
        M = fmaxf(M, pm[((size_t)b * NPART + seg * PER + k) * 32 + ci]);
    red[0][seg][ci] = M;
    __syncthreads();
    float Mg = red[0][0][ci];
#pragma unroll
    for (int q = 1; q < 8; ++q) Mg = fmaxf(Mg, red[0][q][ci]);

    float Z = 0.0f, T = 0.0f;
    for (int k = 0; k < PER; ++k) {
        const size_t i = ((size_t)b * NPART + seg * PER + k) * 32 + ci;
        const float dm = pm[i] - Mg;
        const float e = __expf(dm);
        Z += ps[i] * e;
        if constexpr (ENT) T += (pt[i] + ps[i] * dm) * e;
    }
    red[1][seg][ci] = Z;
    if constexpr (ENT) red[2][seg][ci] = T;
    __syncthreads();
    if (t < 32) {
        float Zt = 0.0f, Tt = 0.0f;
#pragma unroll
        for (int q = 0; q < 8; ++q) {
            Zt += red[1][q][ci];
            if constexpr (ENT) Tt += red[2][q][ci];
        }
        sm[b * 32 + ci] = Mg;
        siz[b * 32 + ci] = 1.0f / Zt;
        if constexpr (ENT)   // ent = (lnZ - T/Z)/ln(32768); eps-in-log ~3e-5
            entp[b * 32 + ci] = (logf(Zt) - Tt / Zt) * (1.0f / 10.39720770839918f);
    }
}

// ---------------------------------------------------------------------------
// Routing iteration (unchanged from round 6, proven).
template <int FINAL>
__global__ __launch_bounds__(256, 4) void k_iter(const unsigned* __restrict__ xu,
                                                 unsigned* __restrict__ Bpk,
                                                 const float* __restrict__ sm,
                                                 const float* __restrict__ siz,
                                                 float* __restrict__ shat,
                                                 float* __restrict__ pm,
                                                 float* __restrict__ ps,
                                                 float* __restrict__ pt) {
    __shared__ float s_m[32], s_z[32];
    const int t = threadIdx.x;
    const size_t loc0 = (size_t)blockIdx.x * 2;
    const int b = (int)(loc0 >> 10);
    if (t < 32) { s_m[t] = sm[b * 32 + t]; s_z[t] = siz[b * 32 + t]; }
    __syncthreads();

    const int l = t >> 7, r = t & 127;
    const int cp = r >> 1, half = r & 1, cj = cp >> 1;
    const size_t loc = loc0 + l;

    const uint4* xr = reinterpret_cast<const uint4*>(xu + loc * 2048 + cp * 32 + half * 16);
    const uint4* Br = reinterpret_cast<const uint4*>(Bpk + loc * 512 + cj * 16 + half * 8);

    uint4 xq[4];
#pragma unroll
    for (int j = 0; j < 4; ++j) xq[j] = xr[j];
    const uint4 bq0 = Br[0], bq1 = Br[1];
    const unsigned bu[8] = {bq0.x, bq0.y, bq0.z, bq0.w, bq1.x, bq1.y, bq1.z, bq1.w};
    float bv[16];
#pragma unroll
    for (int e = 0; e < 8; ++e) { bv[2 * e] = bflo(bu[e]); bv[2 * e + 1] = bfhi(bu[e]); }

    float kk[16];
#pragma unroll
    for (int q = 0; q < 16; ++q)
        kk[q] = __expf(bv[q] - s_m[half * 16 + q]) * s_z[half * 16 + q];

    float S0 = 0.0f, S1 = 0.0f;
#pragma unroll
    for (int j = 0; j < 4; ++j) {
        const unsigned xw[4] = {xq[j].x, xq[j].y, xq[j].z, xq[j].w};
#pragma unroll
        for (int q = 0; q < 4; ++q) {
            S0 = fmaf(kk[j * 4 + q], bflo(xw[q]), S0);
            S1 = fmaf(kk[j * 4 + q], bfhi(xw[q]), S1);
        }
    }
    S0 += __shfl_xor(S0, 1);
    S1 += __shfl_xor(S1, 1);
    const float sh0 = fabsf(S0) * S0 * fastrcp(1.0f + S0 * S0 + EPSF);
    const float sh1 = fabsf(S1) * S1 * fastrcp(1.0f + S1 * S1 + EPSF);

    if constexpr (FINAL) {
        if (half == 0)
            reinterpret_cast<float2*>(shat)[loc * 64 + cp] = make_float2(sh0, sh1);
    } else {
        __shared__ __align__(16) float Bl[2][32][36];
        float d[16];
#pragma unroll
        for (int j = 0; j < 4; ++j) {
            const unsigned xw[4] = {xq[j].x, xq[j].y, xq[j].z, xq[j].w};
#pragma unroll
            for (int q = 0; q < 4; ++q)
                d[j * 4 + q] = fmaf(sh0, bflo(xw[q]), sh1 * bfhi(xw[q]));
        }
#pragma unroll
        for (int q = 0; q < 16; ++q) d[q] += __shfl_xor(d[q], 2);
        if (!(r & 2)) {
            float o[16];
#pragma unroll
            for (int q = 0; q < 16; ++q) o[q] = bv[q] + d[q];
            unsigned pk[8];
#pragma unroll
            for (int e = 0; e < 8; ++e) pk[e] = bfpack2(o[2 * e], o[2 * e + 1]);
            uint4* Bw = reinterpret_cast<uint4*>(Bpk + loc * 512 + cj * 16 + half * 8);
            Bw[0] = make_uint4(pk[0], pk[1], pk[2], pk[3]);
            Bw[1] = make_uint4(pk[4], pk[5], pk[6], pk[7]);
            float4* dst = reinterpret_cast<float4*>(&Bl[l][cj][half * 16]);
            dst[0] = make_float4(o[0], o[1], o[2], o[3]);
            dst[1] = make_float4(o[4], o[5], o[6], o[7]);
            dst[2] = make_float4(o[8], o[9], o[10], o[11]);
            dst[3] = make_float4(o[12], o[13], o[14], o[15]);
        }
        __syncthreads();
        const int l2 = t >> 7, ci = (t >> 2) & 31, qq = t & 3;
        float B8[8];
#pragma unroll
        for (int i = 0; i < 8; ++i) B8[i] = Bl[l2][qq * 8 + i][ci];
        float m = B8[0];
#pragma unroll
        for (int i = 1; i < 8; ++i) m = fmaxf(m, B8[i]);
        m = fmaxf(m, __shfl_xor(m, 1));
        m = fmaxf(m, __shfl_xor(m, 2));
        float s = 0.0f, T = 0.0f;
#pragma unroll
        for (int i = 0; i < 8; ++i) {
            const float dd = B8[i] - m;
            const float e = __expf(dd);
            s += e; T += e * dd;
        }
        s += __shfl_xor(s, 1); s += __shfl_xor(s, 2);
        T += __shfl_xor(T, 1); T += __shfl_xor(T, 2);
        if (qq == 0) {
            const size_t row = (size_t)blockIdx.x * 2 + l2;
            pm[row * 32 + ci] = m;
            ps[row * 32 + ci] = s;
            pt[row * 32 + ci] = T;
        }
    }
}

// ---------------------------------------------------------------------------
// K6: shat [b][h][w][c] -> out [b][c][h][w] ; block 0 finalizes entropy.
__global__ __launch_bounds__(256) void k_out(const float* __restrict__ shat,
                                             const float* __restrict__ entp,
                                             float* __restrict__ out) {
    __shared__ float tile[32][129];
    const int bh = blockIdx.x;
    const int b = bh >> 5, h = bh & 31;
    const int t = threadIdx.x;
    const float4* sp = reinterpret_cast<const float4*>(shat + (size_t)bh * 4096);
#pragma unroll
    for (int j = 0; j < 4; ++j) {
        const int idx = t + j * 256;
        const float4 f = sp[idx];
        const int w = idx >> 5;
        const int c4 = (idx & 31) * 4;
        tile[w][c4 + 0] = f.x; tile[w][c4 + 1] = f.y;
        tile[w][c4 + 2] = f.z; tile[w][c4 + 3] = f.w;
    }
    __syncthreads();
    const int c = t >> 1, half = t & 1;
    float* op = out + (((size_t)b * 128 + c) * 32 + h) * 32 + half * 16;
#pragma unroll
    for (int j = 0; j < 16; ++j) op[j] = tile[half * 16 + j][c];

    if (bh == 0) {
        __shared__ float er[256];
        er[t] = entp[t];
        __syncthreads();
        for (int s2 = 128; s2 > 0; s2 >>= 1) {
            if (t < s2) er[t] += er[t + s2];
            __syncthreads();
        }
        if (t == 0) out[1048576] = er[0] * (1.0f / 256.0f);
    }
}

// ---------------------------------------------------------------------------
extern "C" void kernel_launch(void* const* d_in, const int* in_sizes, int n_in,
                              void* d_out, int out_size, void* d_ws, size_t ws_size,
                              hipStream_t stream) {
    const float* in = (const float*)d_in[0];   // (8,32,8,32,32)
    const float* cw = (const float*)d_in[1];   // (128,1,3,3,3)
    const float* cb = (const float*)d_in[2];   // (128,)
    float* out = (float*)d_out;                // 1048576 + 1 floats

    unsigned* xu  = (unsigned*)d_ws;           // 16,777,216 u32 = 64 MiB
    unsigned* Bpk = xu + 16777216;             //  4,194,304 u32 = 16 MiB
    float* shat = (float*)(Bpk + 4194304);     //  1,048,576 f32 =  4 MiB
    float* pm0  = shat + 1048576;              // [1024*32]
    float* ps0  = pm0 + 32768;
    float* pm1  = ps0 + 32768;                 // [8192*32]
    float* ps1  = pm1 + 262144;
    float* pt1  = ps1 + 262144;
    float* sm0  = pt1 + 262144;                // [256] each
    float* siz0 = sm0 + 256;
    float* sm1  = siz0 + 256;
    float* siz1 = sm1 + 256;
    float* entp = siz1 + 256;

    k_conv_mfma<<<2048, 256, 0, stream>>>(in, cw, cb, xu, Bpk);
    k_bstats<<<1024, 256, 0, stream>>>(Bpk, pm0, ps0);
    k_comb<128, false><<<8, 256, 0, stream>>>(pm0, ps0, nullptr, sm0, siz0, nullptr);
    k_iter<0><<<4096, 256, 0, stream>>>(xu, Bpk, sm0, siz0, nullptr, pm1, ps1, pt1);
    k_comb<1024, true><<<8, 256, 0, stream>>>(pm1, ps1, pt1, sm1, siz1, entp);
    k_iter<1><<<4096, 256, 0, stream>>>(xu, Bpk, sm1, siz1, shat, nullptr, nullptr, nullptr);
    k_out<<<256, 256, 0, stream>>>(shat, entp, out);
}

// Round 8
// 110.805 us; speedup vs baseline: 1.1259x; 1.1259x over previous
//
#include <hip/hip_runtime.h>
#include <hip/hip_bf16.h>

#define EPSF 1e-8f

typedef short bf16x8 __attribute__((ext_vector_type(8)));
typedef float f32x4 __attribute__((ext_vector_type(4)));

// Workspace:
//   Bpk  [loc=8192][lane=64][8 u32]  bf16-packed D-fragment order (16 MiB)
//        pair e = mt*4+nt*2+r2 holds (val[mt][nt][2r2], val[mt][nt][2r2+1])
//        where row(cj) = mt*16+(lane>>4)*4+reg, col(ci) = nt*16+(lane&15)
//   shat [loc][c] f32 (4 MiB)
//   pm0/ps0, pm1/ps1/pt1 [2048][32] ; sm*/siz*/entp [256]

__device__ __forceinline__ float bflo(unsigned u){ return __uint_as_float(u<<16); }
__device__ __forceinline__ float bfhi(unsigned u){ return __uint_as_float(u&0xffff0000u); }
__device__ __forceinline__ float bfu16(unsigned short u){ return __uint_as_float((unsigned)u<<16); }
__device__ __forceinline__ unsigned bfpack2(float a,float b){
    return (__float_as_uint(a)>>16)|(__float_as_uint(b)&0xffff0000u);
}
__device__ __forceinline__ unsigned short bfr16(float a){
    return (unsigned short)(__float_as_uint(a)>>16);
}
__device__ __forceinline__ float fastrcp(float x){ return __builtin_amdgcn_rcpf(x); }

// ---------------------------------------------------------------------------
// One routing iteration, recomputed from taps. PHASE 0: taps->B1+stats0.
// PHASE 1: B1->B2+stats1(+T). PHASE 2: B2->shat. Block = (b,h,4 w's), 4 waves,
// wave = one loc. All per-loc LDS is single-wave (no barriers in main phase).
//
// LDS map (61440 B total -> 2 blocks/CU):
//   0      wLT  u16[28][132]   (weights transposed, conflict-free S-dots)
//   7424   cbL  f32[128]
//   7936   smL  f32[32] ; 8064 sizL f32[32]
//   8192   BIG: slab f32[288][12] (prologue) | per-wave{Blu f32[32][36]; wsL u32[32][20]} = 7168*4
//   36864  vL   u32[4 wave][32 ci][20]   (bf16 pairs of v[ci][k])
//   47104  vTL  u32[4 wave][32 k][20]    (bf16 pairs of vT[k][ci]; row27 = ones)
//   57344  safe: per-wave{shL f32[128]; auxL f32[32]; statb f32[3][32]} = 1024*4
template<int PHASE>
__global__ __launch_bounds__(256, 2) void k_caps(
    const float* __restrict__ in, const float* __restrict__ cw,
    const float* __restrict__ cb, unsigned* __restrict__ Bpk,
    const float* __restrict__ sm_in, const float* __restrict__ siz_in,
    float* __restrict__ pm, float* __restrict__ ps, float* __restrict__ pt,
    float* __restrict__ shat) {
    __shared__ __align__(16) unsigned char smem[61440];
    unsigned short* wLT = (unsigned short*)smem;
    float* cbL  = (float*)(smem + 7424);
    float* smL  = (float*)(smem + 7936);
    float* sizL = (float*)(smem + 8064);
    float* slab = (float*)(smem + 8192);

    const int t = threadIdx.x;
    const int lane = t & 63, wid = t >> 6;
    const int bid = blockIdx.x;
    const int bh = bid >> 3, b = bh >> 5, h = bh & 31;
    const int w0 = (bid & 7) << 2;
    const int l15 = lane & 15, lq = lane >> 4;

    float*    Blu = (float*)(smem + 8192 + wid * 7168);           // [32][36]
    unsigned* wsL = (unsigned*)(smem + 8192 + wid * 7168 + 4608); // [32][20]
    unsigned* vL  = (unsigned*)(smem + 36864 + wid * 2560);
    unsigned* vTL = (unsigned*)(smem + 47104 + wid * 2560);
    float* shL   = (float*)(smem + 57344 + wid * 1024);
    float* auxL  = (float*)(smem + 57344 + wid * 1024 + 512);
    float* statb = (float*)(smem + 57344 + wid * 1024 + 640);

    // ---- prologue: input slab + weights + softmax consts -------------------
    for (int j = t; j < 864; j += 256) {
        const int r = j / 3, q = j - r * 3;
        const int ci2 = r / 9, rem = r - ci2 * 9, kd = rem / 3, dy = rem - kd * 3;
        const int y = h + dy - 1;
        const int x0 = w0 - 4 + q * 4;
        float4 f = {0.f, 0.f, 0.f, 0.f};
        if ((unsigned)y < 32u && (unsigned)x0 < 32u)
            f = *reinterpret_cast<const float4*>(
                in + (((size_t)(b * 32 + ci2) * 8 + kd) * 32 + y) * 32 + x0);
        *reinterpret_cast<float4*>(slab + r * 12 + q * 4) = f;
    }
    for (int j = t; j < 3456; j += 256) {
        const int c = j / 27, k = j - c * 27;
        wLT[k * 132 + c] = bfr16(cw[j]);
    }
    if (t < 128) cbL[t] = cb[t];
    if constexpr (PHASE >= 1) {
        if (t < 32) { smL[t] = sm_in[b * 32 + t]; sizL[t] = siz_in[b * 32 + t]; }
    }
    __syncthreads();

    // ---- taps: v[ci][k], vT[k][ci] (bf16 pairs), vsum (PHASE0) -------------
    {
        const int half = lane & 1, idx = lane >> 1;
        if constexpr (PHASE != 2) {               // v needed for matmul2
            const float* srow = slab + idx * 108 + wid + 3;
            unsigned pk[8];
            if (half == 0) {
#pragma unroll
                for (int j = 0; j < 8; ++j) {
                    float a, bb;
                    { constexpr int k = 0; (void)k; }
                    { const int k = 2 * j;     const int kd = k / 9, r9 = k - kd * 9, dy = r9 / 3, dx = r9 - dy * 3;
                      a  = srow[(kd * 3 + dy) * 12 + dx]; }
                    { const int k = 2 * j + 1; const int kd = k / 9, r9 = k - kd * 9, dy = r9 / 3, dx = r9 - dy * 3;
                      bb = srow[(kd * 3 + dy) * 12 + dx]; }
                    pk[j] = bfpack2(a, bb);
                }
            } else {
#pragma unroll
                for (int j = 0; j < 8; ++j) {
                    const int k0 = 16 + 2 * j, k1 = k0 + 1;
                    float a = 0.f, bb = 0.f;
                    if (k0 < 27) { const int kd = k0 / 9, r9 = k0 - kd * 9, dy = r9 / 3, dx = r9 - dy * 3;
                                   a  = srow[(kd * 3 + dy) * 12 + dx]; }
                    if (k1 < 27) { const int kd = k1 / 9, r9 = k1 - kd * 9, dy = r9 / 3, dx = r9 - dy * 3;
                                   bb = srow[(kd * 3 + dy) * 12 + dx]; }
                    pk[j] = bfpack2(a, bb);
                }
            }
            uint4* dst = (uint4*)(vL + idx * 20 + half * 8);
            dst[0] = make_uint4(pk[0], pk[1], pk[2], pk[3]);
            dst[1] = make_uint4(pk[4], pk[5], pk[6], pk[7]);
        }
        {   // vT row kt = idx ; ci = half*16 + i ; row 27 = ones (K1 column)
            const int kt = idx;
            float vals[16];
            if (kt < 27) {
                const int kd = kt / 9, r9 = kt - kd * 9, dy = r9 / 3, dx = r9 - dy * 3;
                const float* sp = slab + (kd * 3 + dy) * 12 + wid + 3 + dx + (half * 16) * 108;
#pragma unroll
                for (int i = 0; i < 16; ++i) vals[i] = sp[i * 108];
            } else {
                const float fv = (kt == 27) ? 1.0f : 0.0f;
#pragma unroll
                for (int i = 0; i < 16; ++i) vals[i] = fv;
            }
            if constexpr (PHASE >= 1) {
                unsigned pk[8];
#pragma unroll
                for (int j = 0; j < 8; ++j) pk[j] = bfpack2(vals[2 * j], vals[2 * j + 1]);
                uint4* dst = (uint4*)(vTL + kt * 20 + half * 8);
                dst[0] = make_uint4(pk[0], pk[1], pk[2], pk[3]);
                dst[1] = make_uint4(pk[4], pk[5], pk[6], pk[7]);
            } else {
                float vs = 0.f;
#pragma unroll
                for (int i = 0; i < 16; ++i) vs += vals[i];
                vs += __shfl_xor(vs, 1);
                if (half == 0 && kt < 27) auxL[kt] = vs;     // vsum
            }
        }
    }
    __syncthreads();   // slab dead; Blu/wsL (overlaid) become usable

    const size_t loc = (size_t)bh * 32 + w0 + wid;

    // ---- previous B: load, unpack, stage transpose for kmat ---------------
    float b1v[16];
    if constexpr (PHASE >= 1) {
        const uint4* Bg = (const uint4*)(Bpk + loc * 512 + (size_t)lane * 8);
        const uint4 q0 = Bg[0], q1 = Bg[1];
        const unsigned pk[8] = {q0.x, q0.y, q0.z, q0.w, q1.x, q1.y, q1.z, q1.w};
#pragma unroll
        for (int e = 0; e < 8; ++e) { b1v[2 * e] = bflo(pk[e]); b1v[2 * e + 1] = bfhi(pk[e]); }
#pragma unroll
        for (int mt = 0; mt < 2; ++mt)
#pragma unroll
        for (int nt = 0; nt < 2; ++nt)
#pragma unroll
        for (int reg = 0; reg < 4; ++reg)
            Blu[(mt * 16 + lq * 4 + reg) * 36 + nt * 16 + l15] = b1v[mt * 8 + nt * 4 + reg];
    }

    // ---- kmat A-frags + matmul1 (u = kmat x vT) ----------------------------
    if constexpr (PHASE >= 1) {
        float sm8[8], sz8[8];
#pragma unroll
        for (int j = 0; j < 8; ++j) { const int ci = lq * 8 + j; sm8[j] = smL[ci]; sz8[j] = sizL[ci]; }
        bf16x8 kmA[2];
#pragma unroll
        for (int mt = 0; mt < 2; ++mt) {
            const float* rp = Blu + (mt * 16 + l15) * 36 + lq * 8;
            union { unsigned u[4]; bf16x8 v; } cv;
#pragma unroll
            for (int j2 = 0; j2 < 4; ++j2) {
                const float e0 = __expf(rp[2 * j2]     - sm8[2 * j2])     * sz8[2 * j2];
                const float e1 = __expf(rp[2 * j2 + 1] - sm8[2 * j2 + 1]) * sz8[2 * j2 + 1];
                cv.u[j2] = bfpack2(e0, e1);
            }
            kmA[mt] = cv.v;
        }
        bf16x8 vtB[2];
#pragma unroll
        for (int nt = 0; nt < 2; ++nt) {
            union { uint4 q; bf16x8 v; } cv;
            cv.q = *(const uint4*)(vTL + (nt * 16 + l15) * 20 + lq * 4);
            vtB[nt] = cv.v;
        }
        f32x4 accu[2][2];
#pragma unroll
        for (int mt = 0; mt < 2; ++mt)
#pragma unroll
        for (int nt = 0; nt < 2; ++nt) {
            accu[mt][nt] = (f32x4){0.f, 0.f, 0.f, 0.f};
            accu[mt][nt] = __builtin_amdgcn_mfma_f32_16x16x32_bf16(kmA[mt], vtB[nt], accu[mt][nt], 0, 0, 0);
        }
        // u[cj][ktap] -> Blu (overwrite; col 27 = K1[cj])
#pragma unroll
        for (int mt = 0; mt < 2; ++mt)
#pragma unroll
        for (int nt = 0; nt < 2; ++nt)
#pragma unroll
        for (int reg = 0; reg < 4; ++reg)
            Blu[(mt * 16 + lq * 4 + reg) * 36 + nt * 16 + l15] = accu[mt][nt][reg];
    }

    // ---- S + squash (lane handles c = lane and lane+64) --------------------
#pragma unroll
    for (int cc2 = 0; cc2 < 2; ++cc2) {
        const int c = lane + cc2 * 64;
        float S;
        if constexpr (PHASE == 0) {
            S = 0.f;
#pragma unroll
            for (int k = 0; k < 27; ++k) S = fmaf(bfu16(wLT[k * 132 + c]), auxL[k], S);
            S = S * (1.0f / 32768.0f) + cbL[c] * (1.0f / 1024.0f);
        } else {
            const float* up = Blu + (c >> 2) * 36;
            S = cbL[c] * up[27];                       // cb * K1[cj]
#pragma unroll
            for (int k = 0; k < 27; ++k) S = fmaf(bfu16(wLT[k * 132 + c]), up[k], S);
        }
        const float sq = fabsf(S) * S * fastrcp(1.f + S * S + EPSF);
        if constexpr (PHASE == 2) shat[loc * 128 + c] = sq;
        else shL[c] = sq;
    }
    if constexpr (PHASE == 2) return;

    // ---- ws = sum_nj sh*w (bf16) ; cbs = sum_nj sh*cb ----------------------
#pragma unroll
    for (int i = 0; i < 8; ++i) {
        const int cj = lq + 4 * i;
        const int k0 = 2 * l15, k1 = k0 + 1;
        float v0 = 0.f, v1 = 0.f;
        if (k0 < 27) {
#pragma unroll
            for (int nj = 0; nj < 4; ++nj)
                v0 = fmaf(shL[cj * 4 + nj], bfu16(wLT[k0 * 132 + cj * 4 + nj]), v0);
        }
        if (k1 < 27) {
#pragma unroll
            for (int nj = 0; nj < 4; ++nj)
                v1 = fmaf(shL[cj * 4 + nj], bfu16(wLT[k1 * 132 + cj * 4 + nj]), v1);
        }
        wsL[cj * 20 + l15] = bfpack2(v0, v1);
    }
    if (lane < 32) {
        float cv = 0.f;
#pragma unroll
        for (int nj = 0; nj < 4; ++nj) cv = fmaf(shL[lane * 4 + nj], cbL[lane * 4 + nj], cv);
        auxL[lane] = cv;    // cbs (PHASE0: overwrites vsum after its last use)
    }

    // ---- matmul2: B_upd = ws x v -------------------------------------------
    bf16x8 wsA[2], vB[2];
#pragma unroll
    for (int mt = 0; mt < 2; ++mt) {
        union { uint4 q; bf16x8 v; } cv;
        cv.q = *(const uint4*)(wsL + (mt * 16 + l15) * 20 + lq * 4);
        wsA[mt] = cv.v;
    }
#pragma unroll
    for (int nt = 0; nt < 2; ++nt) {
        union { uint4 q; bf16x8 v; } cv;
        cv.q = *(const uint4*)(vL + (nt * 16 + l15) * 20 + lq * 4);
        vB[nt] = cv.v;
    }
    f32x4 accb[2][2];
#pragma unroll
    for (int mt = 0; mt < 2; ++mt)
#pragma unroll
    for (int nt = 0; nt < 2; ++nt) {
        accb[mt][nt] = (f32x4){0.f, 0.f, 0.f, 0.f};
        accb[mt][nt] = __builtin_amdgcn_mfma_f32_16x16x32_bf16(wsA[mt], vB[nt], accb[mt][nt], 0, 0, 0);
    }

    // ---- B_new = [B_prev +] upd + cbs ; pack ; store ; stats ---------------
    float cbs8[2][4];
#pragma unroll
    for (int mt = 0; mt < 2; ++mt)
#pragma unroll
    for (int reg = 0; reg < 4; ++reg) cbs8[mt][reg] = auxL[mt * 16 + lq * 4 + reg];

    float bnew[16];
#pragma unroll
    for (int mt = 0; mt < 2; ++mt)
#pragma unroll
    for (int nt = 0; nt < 2; ++nt)
#pragma unroll
    for (int reg = 0; reg < 4; ++reg) {
        float val = accb[mt][nt][reg] + cbs8[mt][reg];
        if constexpr (PHASE == 1) val += b1v[mt * 8 + nt * 4 + reg];
        bnew[mt * 8 + nt * 4 + reg] = val;
    }
    {
        unsigned pk[8];
#pragma unroll
        for (int e = 0; e < 8; ++e) pk[e] = bfpack2(bnew[2 * e], bnew[2 * e + 1]);
        uint4* Bg = (uint4*)(Bpk + loc * 512 + (size_t)lane * 8);
        Bg[0] = make_uint4(pk[0], pk[1], pk[2], pk[3]);
        Bg[1] = make_uint4(pk[4], pk[5], pk[6], pk[7]);
    }
    // per-ci stats over 32 cj: 8 in-lane, then lanes l^16, l^32 share ci
    float m2[2], s2[2], T2[2];
#pragma unroll
    for (int nt = 0; nt < 2; ++nt) {
        float m = -1e30f;
#pragma unroll
        for (int mt = 0; mt < 2; ++mt)
#pragma unroll
        for (int reg = 0; reg < 4; ++reg) m = fmaxf(m, bnew[mt * 8 + nt * 4 + reg]);
        float s = 0.f, T = 0.f;
#pragma unroll
        for (int mt = 0; mt < 2; ++mt)
#pragma unroll
        for (int reg = 0; reg < 4; ++reg) {
            const float d = bnew[mt * 8 + nt * 4 + reg] - m;
            const float e = __expf(d);
            s += e; T += e * d;
        }
        m2[nt] = m; s2[nt] = s; T2[nt] = T;
#pragma unroll
        for (int off = 16; off <= 32; off <<= 1) {
            const float mo = __shfl_xor(m2[nt], off);
            const float so = __shfl_xor(s2[nt], off);
            const float To = __shfl_xor(T2[nt], off);
            const float nm = fmaxf(m2[nt], mo);
            const float ea = __expf(m2[nt] - nm), eb = __expf(mo - nm);
            T2[nt] = ea * (T2[nt] + s2[nt] * (m2[nt] - nm)) + eb * (To + so * (mo - nm));
            s2[nt] = ea * s2[nt] + eb * so;
            m2[nt] = nm;
        }
    }
    if (lane < 16) {
#pragma unroll
        for (int nt = 0; nt < 2; ++nt) {
            const int ci = nt * 16 + lane;
            statb[ci] = m2[nt]; statb[32 + ci] = s2[nt]; statb[64 + ci] = T2[nt];
        }
    }
    __syncthreads();
    if (t < 32) {    // combine 4 waves -> block partial
        float M = -1e30f, Z = 0.f, T = 0.f;
#pragma unroll
        for (int wv = 0; wv < 4; ++wv) {
            const float* sw = (const float*)(smem + 57344 + wv * 1024 + 640);
            const float mo = sw[t], so = sw[32 + t], To = sw[64 + t];
            const float nm = fmaxf(M, mo);
            const float ea = __expf(M - nm), eb = __expf(mo - nm);
            T = ea * (T + Z * (M - nm)) + eb * (To + so * (mo - nm));
            Z = ea * Z + eb * so;
            M = nm;
        }
        pm[bid * 32 + t] = M;
        ps[bid * 32 + t] = Z;
        if constexpr (PHASE == 1) pt[bid * 32 + t] = T;
    }
}

// ---------------------------------------------------------------------------
// Combine NPART partials per (b,ci) -> sm, siz (+ entropy partial if ENT).
template <int NPART, bool ENT>
__global__ __launch_bounds__(256) void k_comb(const float* __restrict__ pm,
                                              const float* __restrict__ ps,
                                              const float* __restrict__ pt,
                                              float* __restrict__ sm,
                                              float* __restrict__ siz,
                                              float* __restrict__ entp) {
    const int b = blockIdx.x, t = threadIdx.x;
    const int ci = t & 31, seg = t >> 5;
    constexpr int PER = NPART / 8;
    __shared__ float red[3][8][33];

    float M = -1e30f;
    for (int k = 0; k < PER; ++k)
        M = fmaxf(M, pm[((size_t)b * NPART + seg * PER + k) * 32 + ci]);
    red[0][seg][ci] = M;
    __syncthreads();
    float Mg = red[0][0][ci];
#pragma unroll
    for (int q = 1; q < 8; ++q) Mg = fmaxf(Mg, red[0][q][ci]);

    float Z = 0.0f, T = 0.0f;
    for (int k = 0; k < PER; ++k) {
        const size_t i = ((size_t)b * NPART + seg * PER + k) * 32 + ci;
        const float dm = pm[i] - Mg;
        const float e = __expf(dm);
        Z += ps[i] * e;
        if constexpr (ENT) T += (pt[i] + ps[i] * dm) * e;
    }
    red[1][seg][ci] = Z;
    if constexpr (ENT) red[2][seg][ci] = T;
    __syncthreads();
    if (t < 32) {
        float Zt = 0.0f, Tt = 0.0f;
#pragma unroll
        for (int q = 0; q < 8; ++q) {
            Zt += red[1][q][ci];
            if constexpr (ENT) Tt += red[2][q][ci];
        }
        sm[b * 32 + ci] = Mg;
        siz[b * 32 + ci] = 1.0f / Zt;
        if constexpr (ENT)   // ent = (lnZ - T/Z)/ln(32768); eps-in-log ~3e-5
            entp[b * 32 + ci] = (logf(Zt) - Tt / Zt) * (1.0f / 10.39720770839918f);
    }
}

// ---------------------------------------------------------------------------
// shat [b][h][w][c] -> out [b][c][h][w] ; block 0 finalizes entropy.
__global__ __launch_bounds__(256) void k_out(const float* __restrict__ shat,
                                             const float* __restrict__ entp,
                                             float* __restrict__ out) {
    __shared__ float tile[32][129];
    const int bh = blockIdx.x;
    const int b = bh >> 5, h = bh & 31;
    const int t = threadIdx.x;
    const float4* sp = reinterpret_cast<const float4*>(shat + (size_t)bh * 4096);
#pragma unroll
    for (int j = 0; j < 4; ++j) {
        const int idx = t + j * 256;
        const float4 f = sp[idx];
        const int w = idx >> 5;
        const int c4 = (idx & 31) * 4;
        tile[w][c4 + 0] = f.x; tile[w][c4 + 1] = f.y;
        tile[w][c4 + 2] = f.z; tile[w][c4 + 3] = f.w;
    }
    __syncthreads();
    const int c = t >> 1, half = t & 1;
    float* op = out + (((size_t)b * 128 + c) * 32 + h) * 32 + half * 16;
#pragma unroll
    for (int j = 0; j < 16; ++j) op[j] = tile[half * 16 + j][c];

    if (bh == 0) {
        __shared__ float er[256];
        er[t] = entp[t];
        __syncthreads();
        for (int s2 = 128; s2 > 0; s2 >>= 1) {
            if (t < s2) er[t] += er[t + s2];
            __syncthreads();
        }
        if (t == 0) out[1048576] = er[0] * (1.0f / 256.0f);
    }
}

// ---------------------------------------------------------------------------
extern "C" void kernel_launch(void* const* d_in, const int* in_sizes, int n_in,
                              void* d_out, int out_size, void* d_ws, size_t ws_size,
                              hipStream_t stream) {
    const float* in = (const float*)d_in[0];   // (8,32,8,32,32)
    const float* cw = (const float*)d_in[1];   // (128,1,3,3,3)
    const float* cb = (const float*)d_in[2];   // (128,)
    float* out = (float*)d_out;                // 1048576 + 1 floats

    unsigned* Bpk = (unsigned*)d_ws;           // 8192*512 u32 = 16 MiB
    float* shat = (float*)(Bpk + 4194304);     // 1,048,576 f32 = 4 MiB
    float* pm0  = shat + 1048576;              // [2048*32] each
    float* ps0  = pm0 + 65536;
    float* pm1  = ps0 + 65536;
    float* ps1  = pm1 + 65536;
    float* pt1  = ps1 + 65536;
    float* sm0  = pt1 + 65536;                 // [256] each
    float* siz0 = sm0 + 256;
    float* sm1  = siz0 + 256;
    float* siz1 = sm1 + 256;
    float* entp = siz1 + 256;

    k_caps<0><<<2048, 256, 0, stream>>>(in, cw, cb, Bpk, sm0, siz0, pm0, ps0, pt1, shat);
    k_comb<256, false><<<8, 256, 0, stream>>>(pm0, ps0, nullptr, sm0, siz0, nullptr);
    k_caps<1><<<2048, 256, 0, stream>>>(in, cw, cb, Bpk, sm0, siz0, pm1, ps1, pt1, shat);
    k_comb<256, true><<<8, 256, 0, stream>>>(pm1, ps1, pt1, sm1, siz1, entp);
    k_caps<2><<<2048, 256, 0, stream>>>(in, cw, cb, Bpk, sm1, siz1, pm1, ps1, pt1, shat);
    k_out<<<256, 256, 0, stream>>>(shat, entp, out);
}